// Round 1
// baseline (885.436 us; speedup 1.0000x reference)
//
#include <hip/hip_runtime.h>
#include <cstdint>
#include <cstddef>

typedef unsigned short u16;
typedef unsigned int   u32;
typedef __attribute__((ext_vector_type(8))) short bf16x8;   // 8 bf16 in 4 VGPRs
typedef __attribute__((ext_vector_type(4))) float f32x4;

#define ALPHA 0.05f
#define OMA   0.95f

__device__ __forceinline__ u16 f2b(float f) {
  u32 u = __float_as_uint(f);
  u = (u + 0x7fffu + ((u >> 16) & 1u)) >> 16;   // RNE f32->bf16
  return (u16)u;
}

__device__ __forceinline__ void gld16(const void* g, void* l) {
  __builtin_amdgcn_global_load_lds((const __attribute__((address_space(1))) u32*)g,
                                   (__attribute__((address_space(3))) u32*)l, 16, 0, 0);
}

// ---------------------------------------------------------------------------
// K0: Abar = 0.95 * rownorm(adj + I). Writes fp32 Abar and bf16 into G[:,0:512]
// ---------------------------------------------------------------------------
__global__ __launch_bounds__(256) void k_norm(const float* __restrict__ adj,
                                              float* __restrict__ Af,
                                              u16* __restrict__ G) {
  int v = blockIdx.x;      // 512
  int t = threadIdx.x;     // 256
  float a0 = adj[(size_t)v * 512 + t]       + (t == v ? 1.f : 0.f);
  float a1 = adj[(size_t)v * 512 + t + 256] + (t + 256 == v ? 1.f : 0.f);
  float s = a0 + a1;
  for (int off = 32; off; off >>= 1) s += __shfl_down(s, off);
  __shared__ float ws4[4];
  if ((t & 63) == 0) ws4[t >> 6] = s;
  __syncthreads();
  float inv = OMA / (ws4[0] + ws4[1] + ws4[2] + ws4[3]);
  float b0 = a0 * inv, b1 = a1 * inv;
  Af[(size_t)v * 512 + t]       = b0;
  Af[(size_t)v * 512 + t + 256] = b1;
  G[(size_t)v * 1536 + t]       = f2b(b0);
  G[(size_t)v * 1536 + t + 256] = f2b(b1);
}

// ---------------------------------------------------------------------------
// K1/K2: P = L @ R (512x512 fp32). Optionally store fp32 P; store bf16 into
// G[:, gcol:gcol+512].
// ---------------------------------------------------------------------------
__global__ __launch_bounds__(256) void k_pow(const float* __restrict__ L,
                                             const float* __restrict__ R,
                                             float* __restrict__ Pf,
                                             u16* __restrict__ G, int gcol) {
  __shared__ float lrow[4][512];
  int r0 = blockIdx.x * 4;   // 128 blocks
  int t = threadIdx.x;       // 256
  for (int i = t; i < 4 * 512; i += 256)
    lrow[i >> 9][i & 511] = L[(size_t)(r0 + (i >> 9)) * 512 + (i & 511)];
  __syncthreads();
  float acc[4][2] = {};
  for (int k = 0; k < 512; ++k) {
    float rk0 = R[(size_t)k * 512 + t];
    float rk1 = R[(size_t)k * 512 + t + 256];
#pragma unroll
    for (int r = 0; r < 4; ++r) {
      float lv = lrow[r][k];
      acc[r][0] += lv * rk0;
      acc[r][1] += lv * rk1;
    }
  }
  for (int r = 0; r < 4; ++r) {
    if (Pf) {
      Pf[(size_t)(r0 + r) * 512 + t]       = acc[r][0];
      Pf[(size_t)(r0 + r) * 512 + t + 256] = acc[r][1];
    }
    G[(size_t)(r0 + r) * 1536 + gcol + t]       = f2b(acc[r][0]);
    G[(size_t)(r0 + r) * 1536 + gcol + t + 256] = f2b(acc[r][1]);
  }
}

// ---------------------------------------------------------------------------
// K3: U[R=o*4+j][c]  (bf16, 128x32) from W[32][128]
// ---------------------------------------------------------------------------
__global__ void k_u(const float* __restrict__ W, u16* __restrict__ U) {
  int R = threadIdx.x;   // 128
  int o = R >> 2, j = R & 3;
  for (int c = 0; c < 32; ++c) {
    float w0 = W[o * 128 + c];
    float w1 = W[o * 128 + 32 + c];
    float w2 = W[o * 128 + 64 + c];
    float w3 = W[o * 128 + 96 + c];
    float u;
    if (j == 0)      u = w0 + ALPHA * (w1 + w2 + w3);
    else if (j == 1) u = w1 + ALPHA * (w2 + w3);
    else if (j == 2) u = w2 + ALPHA * w3;
    else             u = w3;
    U[R * 32 + c] = f2b(u);
  }
}

// ---------------------------------------------------------------------------
// P1 (k_mix): per (n, v-block16, l-block32): C_j = U_j @ x  via one
// mfma_f32_16x16x32_bf16 per 16x16 tile (K=32 = channel dim, done in one shot).
// Writes j=0 result (C0) as fp32 directly into d_out (y), j=1..3 as bf16 into
// C[n-local][o][l][k'] with k' = (j-1)*512 + w  (N-major, K-contig for P2).
// ---------------------------------------------------------------------------
__global__ __launch_bounds__(256) void k_mix(const float* __restrict__ x,
                                             const u16* __restrict__ Uw,
                                             u16* __restrict__ C,
                                             float* __restrict__ y,
                                             int n0) {
  __shared__ u16 slab[512 * 32];   // [p][c], p = l*16 + v   (32 KB)
  __shared__ u16 Ul[128 * 32];     // [R][c]                 (8 KB)
  int t = threadIdx.x;
  // XCD-aware swizzle: contiguous virt ranges per XCD (grid is multiple of 8)
  int chunk = gridDim.x >> 3;
  int rb = blockIdx.x;
  int virt = (rb & 7) * chunk + (rb >> 3);
  int q  = virt & 511;
  int n  = n0 + (virt >> 9);
  int v0 = (q & 31) << 4;    // v-block of 16
  int l0 = (q >> 5) << 5;    // l-block of 32

  // stage U: 8192 B via 2 async calls (linear)
  gld16(Uw + t * 8,        (char*)Ul + ((t >> 6) << 10));
  gld16(Uw + 2048 + t * 8, (char*)Ul + 4096 + ((t >> 6) << 10));

  // fill slab: thread handles x rows (c=t&31, v=(t>>5)) and (c, v+8); each row
  // is a full 128B cache line (l0..l0+31).
  int c = t & 31;
  int v = t >> 5;   // 0..7
#pragma unroll
  for (int h = 0; h < 2; ++h) {
    int vv = v + h * 8;
    const float* xp = x + (((size_t)(n * 32 + c) * 512 + v0 + vv) << 9) + l0;
#pragma unroll
    for (int f = 0; f < 8; ++f) {
      float4 d = *(const float4*)(xp + f * 4);
      int p = (f * 4) * 16 + vv;       // p = l*16 + v
      slab[(p + 0)  * 32 + c] = f2b(d.x);
      slab[(p + 16) * 32 + c] = f2b(d.y);
      slab[(p + 32) * 32 + c] = f2b(d.z);
      slab[(p + 48) * 32 + c] = f2b(d.w);
    }
  }
  __syncthreads();

  int lane = t & 63, wid = t >> 6;
  int l15 = lane & 15, g = lane >> 4;

  bf16x8 a[8], b[8];
#pragma unroll
  for (int mt = 0; mt < 8; ++mt)
    a[mt] = *(const bf16x8*)(Ul + (mt * 16 + l15) * 32 + g * 8);
#pragma unroll
  for (int i = 0; i < 8; ++i) {
    int p = (wid * 8 + i) * 16 + l15;
    b[i] = *(const bf16x8*)(slab + p * 32 + g * 8);
  }

  int nol_base = (n - n0) * 32;
#pragma unroll
  for (int mt = 0; mt < 8; ++mt) {
    int o = mt * 4 + g;                 // D row = mt*16 + g*4 + reg ; o=R/4, j=reg
    size_t ybase = (((size_t)(n * 32 + o) * 512 + v0 + l15) << 9) + l0;
    size_t cbase = ((size_t)(nol_base + o) * 512 + l0) * 1536 + v0 + l15;
#pragma unroll
    for (int i = 0; i < 8; ++i) {
      f32x4 z = {0.f, 0.f, 0.f, 0.f};
      f32x4 acc = __builtin_amdgcn_mfma_f32_16x16x32_bf16(a[mt], b[i], z, 0, 0, 0);
      int nt = wid * 8 + i;             // = l index within block; D col v = l15
      y[ybase + nt] = acc[0];                                  // j=0 -> C0 (fp32)
      C[cbase + (size_t)nt * 1536 +    0] = f2b(acc[1]);       // j=1
      C[cbase + (size_t)nt * 1536 +  512] = f2b(acc[2]);       // j=2
      C[cbase + (size_t)nt * 1536 + 1024] = f2b(acc[3]);       // j=3
    }
  }
}

// ---------------------------------------------------------------------------
// P2 (k_gemm): per (n,o): y[512,512] = G[512,1536] @ C[no][*,1536]^T + C0 + b.
// m97-style 128x128 tile, BK=32, 4 waves (2x2 of 64x64), global_load_lds w=16,
// b128 fragment reads on both operands (both K-contig). 48 K-steps.
// ---------------------------------------------------------------------------
__global__ __launch_bounds__(256) void k_gemm(const u16* __restrict__ G,
                                              const u16* __restrict__ C,
                                              const float* __restrict__ bias,
                                              float* __restrict__ y,
                                              int n0) {
  __shared__ u16 At[128 * 32];
  __shared__ u16 Bt[128 * 32];
  int t = threadIdx.x;
  int chunk = gridDim.x >> 3;
  int rb = blockIdx.x;
  int virt = (rb & 7) * chunk + (rb >> 3);
  int q  = virt & 511;
  int n  = n0 + (virt >> 9);
  int o  = q >> 4;
  int lt = (q >> 2) & 3;
  int vt = q & 3;                 // vt fastest: 4 consecutive blocks share B panel
  int v0 = vt << 7, l0 = lt << 7;
  const u16* Cp = C + (size_t)((n - n0) * 32 + o) * (512 * 1536);

  int lane = t & 63, wid = t >> 6;
  int l15 = lane & 15, g = lane >> 4;
  int wr = wid >> 1, wc = wid & 1;

  f32x4 acc[4][4];
#pragma unroll
  for (int i = 0; i < 4; ++i)
#pragma unroll
    for (int j = 0; j < 4; ++j) {
      f32x4 z = {0.f, 0.f, 0.f, 0.f};
      acc[i][j] = z;
    }

  int arow = t >> 2;              // 0..63
  int kch  = (t & 3) << 3;        // 0,8,16,24
  const u16* ga0 = G  + (size_t)(v0 + arow)      * 1536 + kch;
  const u16* ga1 = G  + (size_t)(v0 + 64 + arow) * 1536 + kch;
  const u16* gb0 = Cp + (size_t)(l0 + arow)      * 1536 + kch;
  const u16* gb1 = Cp + (size_t)(l0 + 64 + arow) * 1536 + kch;
  char* la = (char*)At + ((t >> 6) << 10);
  char* lb = (char*)Bt + ((t >> 6) << 10);

  for (int ks = 0; ks < 1536; ks += 32) {
    gld16(ga0 + ks, la);
    gld16(ga1 + ks, la + 4096);
    gld16(gb0 + ks, lb);
    gld16(gb1 + ks, lb + 4096);
    __syncthreads();
    bf16x8 a[4], b[4];
#pragma unroll
    for (int i = 0; i < 4; ++i) {
      a[i] = *(const bf16x8*)(At + (wr * 64 + i * 16 + l15) * 32 + g * 8);
      b[i] = *(const bf16x8*)(Bt + (wc * 64 + i * 16 + l15) * 32 + g * 8);
    }
#pragma unroll
    for (int mi = 0; mi < 4; ++mi)
#pragma unroll
      for (int ni = 0; ni < 4; ++ni)
        acc[mi][ni] = __builtin_amdgcn_mfma_f32_16x16x32_bf16(a[mi], b[ni], acc[mi][ni], 0, 0, 0);
    __syncthreads();
  }

  float bo = bias[o];
#pragma unroll
  for (int mi = 0; mi < 4; ++mi)
#pragma unroll
    for (int ni = 0; ni < 4; ++ni)
#pragma unroll
      for (int r = 0; r < 4; ++r) {
        int vv = v0 + wr * 64 + mi * 16 + g * 4 + r;
        int ll = l0 + wc * 64 + ni * 16 + l15;
        size_t idx = (((size_t)(n * 32 + o) * 512 + vv) << 9) + ll;
        y[idx] += acc[mi][ni][r] + bo;   // y holds C0 from k_mix
      }
}

// ---------------------------------------------------------------------------
extern "C" void kernel_launch(void* const* d_in, const int* in_sizes, int n_in,
                              void* d_out, int out_size, void* d_ws, size_t ws_size,
                              hipStream_t stream) {
  (void)in_sizes; (void)n_in; (void)out_size;
  const float* x    = (const float*)d_in[0];
  const float* adj  = (const float*)d_in[1];
  const float* W    = (const float*)d_in[2];
  const float* bias = (const float*)d_in[3];
  float* y = (float*)d_out;
  char* ws = (char*)d_ws;

  // ws layout
  u16*   G  = (u16*)(ws);                  // 512*1536*2      = 1,572,864
  float* Af = (float*)(ws + 1572864);      // 512*512*4       = 1,048,576
  float* A2 = (float*)(ws + 2621440);      // 512*512*4       = 1,048,576
  u16*   U  = (u16*)(ws + 3670016);        // 128*32*2        = 8,192
  u16*   C  = (u16*)(ws + 3678208);        // per-n: 32*512*1536*2 = 50,331,648
  const size_t fixed = 3678208;
  const size_t per_n = (size_t)32 * 512 * 1536 * 2;

  int grp = 0;
  const int cands[4] = {8, 4, 2, 1};
  for (int i = 0; i < 4; ++i)
    if (fixed + (size_t)cands[i] * per_n <= ws_size) { grp = cands[i]; break; }
  if (!grp) return;  // workspace too small: fail loudly via validation

  k_norm<<<dim3(512), dim3(256), 0, stream>>>(adj, Af, G);
  k_pow <<<dim3(128), dim3(256), 0, stream>>>(Af, Af, A2, G, 512);
  k_pow <<<dim3(128), dim3(256), 0, stream>>>(A2, Af, (float*)nullptr, G, 1024);
  k_u   <<<dim3(1),   dim3(128), 0, stream>>>(W, U);

  for (int n0 = 0; n0 < 8; n0 += grp) {
    k_mix <<<dim3(grp * 512), dim3(256), 0, stream>>>(x, U, C, y, n0);
    k_gemm<<<dim3(grp * 512), dim3(256), 0, stream>>>(G, C, bias, y, n0);
  }
}

// Round 2
// 824.690 us; speedup vs baseline: 1.0737x; 1.0737x over previous
//
#include <hip/hip_runtime.h>
#include <cstdint>
#include <cstddef>

typedef unsigned short u16;
typedef unsigned int   u32;
typedef __attribute__((ext_vector_type(8))) short bf16x8;   // 8 bf16 in 4 VGPRs
typedef __attribute__((ext_vector_type(4))) float f32x4;

#define ALPHA 0.05f
#define OMA   0.95f

__device__ __forceinline__ u16 f2b(float f) {
  u32 u = __float_as_uint(f);
  u = (u + 0x7fffu + ((u >> 16) & 1u)) >> 16;   // RNE f32->bf16
  return (u16)u;
}

__device__ __forceinline__ void gld16(const void* g, void* l) {
  __builtin_amdgcn_global_load_lds((const __attribute__((address_space(1))) u32*)g,
                                   (__attribute__((address_space(3))) u32*)l, 16, 0, 0);
}

// ---------------------------------------------------------------------------
// K0: Abar = 0.95 * rownorm(adj + I). Writes fp32 Abar and bf16 into G[:,0:512]
// ---------------------------------------------------------------------------
__global__ __launch_bounds__(256) void k_norm(const float* __restrict__ adj,
                                              float* __restrict__ Af,
                                              u16* __restrict__ G) {
  int v = blockIdx.x;      // 512
  int t = threadIdx.x;     // 256
  float a0 = adj[(size_t)v * 512 + t]       + (t == v ? 1.f : 0.f);
  float a1 = adj[(size_t)v * 512 + t + 256] + (t + 256 == v ? 1.f : 0.f);
  float s = a0 + a1;
  for (int off = 32; off; off >>= 1) s += __shfl_down(s, off);
  __shared__ float ws4[4];
  if ((t & 63) == 0) ws4[t >> 6] = s;
  __syncthreads();
  float inv = OMA / (ws4[0] + ws4[1] + ws4[2] + ws4[3]);
  float b0 = a0 * inv, b1 = a1 * inv;
  Af[(size_t)v * 512 + t]       = b0;
  Af[(size_t)v * 512 + t + 256] = b1;
  G[(size_t)v * 1536 + t]       = f2b(b0);
  G[(size_t)v * 1536 + t + 256] = f2b(b1);
}

// ---------------------------------------------------------------------------
// K1/K2: P = L @ R (512x512 fp32). Optionally store fp32 P; store bf16 into
// G[:, gcol:gcol+512].
// ---------------------------------------------------------------------------
__global__ __launch_bounds__(256) void k_pow(const float* __restrict__ L,
                                             const float* __restrict__ R,
                                             float* __restrict__ Pf,
                                             u16* __restrict__ G, int gcol) {
  __shared__ float lrow[4][512];
  int r0 = blockIdx.x * 4;   // 128 blocks
  int t = threadIdx.x;       // 256
  for (int i = t; i < 4 * 512; i += 256)
    lrow[i >> 9][i & 511] = L[(size_t)(r0 + (i >> 9)) * 512 + (i & 511)];
  __syncthreads();
  float acc[4][2] = {};
  for (int k = 0; k < 512; ++k) {
    float rk0 = R[(size_t)k * 512 + t];
    float rk1 = R[(size_t)k * 512 + t + 256];
#pragma unroll
    for (int r = 0; r < 4; ++r) {
      float lv = lrow[r][k];
      acc[r][0] += lv * rk0;
      acc[r][1] += lv * rk1;
    }
  }
  for (int r = 0; r < 4; ++r) {
    if (Pf) {
      Pf[(size_t)(r0 + r) * 512 + t]       = acc[r][0];
      Pf[(size_t)(r0 + r) * 512 + t + 256] = acc[r][1];
    }
    G[(size_t)(r0 + r) * 1536 + gcol + t]       = f2b(acc[r][0]);
    G[(size_t)(r0 + r) * 1536 + gcol + t + 256] = f2b(acc[r][1]);
  }
}

// ---------------------------------------------------------------------------
// K3: U[R=o*4+j][c]  (bf16, 128x32) from W[32][128]
// ---------------------------------------------------------------------------
__global__ void k_u(const float* __restrict__ W, u16* __restrict__ U) {
  int R = threadIdx.x;   // 128
  int o = R >> 2, j = R & 3;
  for (int c = 0; c < 32; ++c) {
    float w0 = W[o * 128 + c];
    float w1 = W[o * 128 + 32 + c];
    float w2 = W[o * 128 + 64 + c];
    float w3 = W[o * 128 + 96 + c];
    float u;
    if (j == 0)      u = w0 + ALPHA * (w1 + w2 + w3);
    else if (j == 1) u = w1 + ALPHA * (w2 + w3);
    else if (j == 2) u = w2 + ALPHA * w3;
    else             u = w3;
    U[R * 32 + c] = f2b(u);
  }
}

// ---------------------------------------------------------------------------
// P1 (k_mix): per (n, v-block16, l-block32): C_j = U_j @ x  via one
// mfma_f32_16x16x32_bf16 per 16x16 tile (K=32 = channel dim, done in one shot).
// Writes j=0 result (C0) as fp32 directly into d_out (y), j=1..3 as bf16 into
// C[n-local][o][l][k'] with k' = (j-1)*512 + w  (N-major, K-contig for P2).
// ---------------------------------------------------------------------------
__global__ __launch_bounds__(256) void k_mix(const float* __restrict__ x,
                                             const u16* __restrict__ Uw,
                                             u16* __restrict__ C,
                                             float* __restrict__ y,
                                             int n0) {
  __shared__ u16 slab[512 * 32];   // [p][c], p = l*16 + v   (32 KB)
  __shared__ u16 Ul[128 * 32];     // [R][c]                 (8 KB)
  int t = threadIdx.x;
  int chunk = gridDim.x >> 3;
  int rb = blockIdx.x;
  int virt = (rb & 7) * chunk + (rb >> 3);
  int q  = virt & 511;
  int n  = n0 + (virt >> 9);
  int v0 = (q & 31) << 4;    // v-block of 16
  int l0 = (q >> 5) << 5;    // l-block of 32

  gld16(Uw + t * 8,        (char*)Ul + ((t >> 6) << 10));
  gld16(Uw + 2048 + t * 8, (char*)Ul + 4096 + ((t >> 6) << 10));

  int c = t & 31;
  int v = t >> 5;   // 0..7
#pragma unroll
  for (int h = 0; h < 2; ++h) {
    int vv = v + h * 8;
    const float* xp = x + (((size_t)(n * 32 + c) * 512 + v0 + vv) << 9) + l0;
#pragma unroll
    for (int f = 0; f < 8; ++f) {
      float4 d = *(const float4*)(xp + f * 4);
      int p = (f * 4) * 16 + vv;       // p = l*16 + v
      slab[(p + 0)  * 32 + c] = f2b(d.x);
      slab[(p + 16) * 32 + c] = f2b(d.y);
      slab[(p + 32) * 32 + c] = f2b(d.z);
      slab[(p + 48) * 32 + c] = f2b(d.w);
    }
  }
  __syncthreads();

  int lane = t & 63, wid = t >> 6;
  int l15 = lane & 15, g = lane >> 4;

  bf16x8 a[8], b[8];
#pragma unroll
  for (int mt = 0; mt < 8; ++mt)
    a[mt] = *(const bf16x8*)(Ul + (mt * 16 + l15) * 32 + g * 8);
#pragma unroll
  for (int i = 0; i < 8; ++i) {
    int p = (wid * 8 + i) * 16 + l15;
    b[i] = *(const bf16x8*)(slab + p * 32 + g * 8);
  }

  int nol_base = (n - n0) * 32;
#pragma unroll
  for (int mt = 0; mt < 8; ++mt) {
    int o = mt * 4 + g;                 // D row = mt*16 + g*4 + reg ; o=R/4, j=reg
    size_t ybase = (((size_t)(n * 32 + o) * 512 + v0 + l15) << 9) + l0;
    size_t cbase = ((size_t)(nol_base + o) * 512 + l0) * 1536 + v0 + l15;
#pragma unroll
    for (int i = 0; i < 8; ++i) {
      f32x4 z = {0.f, 0.f, 0.f, 0.f};
      f32x4 acc = __builtin_amdgcn_mfma_f32_16x16x32_bf16(a[mt], b[i], z, 0, 0, 0);
      int nt = wid * 8 + i;             // = l index within block; D col v = l15
      y[ybase + nt] = acc[0];                                  // j=0 -> C0 (fp32)
      C[cbase + (size_t)nt * 1536 +    0] = f2b(acc[1]);       // j=1
      C[cbase + (size_t)nt * 1536 +  512] = f2b(acc[2]);       // j=2
      C[cbase + (size_t)nt * 1536 + 1024] = f2b(acc[3]);       // j=3
    }
  }
}

// ---------------------------------------------------------------------------
// P2 (k_gemm): per (n,o): y[512,512] = G[512,1536] @ C[no][*,1536]^T + C0 + b.
// 128x128 tile, BK=64, 2-phase pipeline (issue next-tile global_load_lds,
// compute current, one barrier), XOR-swizzled LDS (byte ^= (row&7)<<4) applied
// as pre-swizzled global source + swizzled ds_read (rule 21).
// ---------------------------------------------------------------------------
__global__ __launch_bounds__(256) void k_gemm(const u16* __restrict__ G,
                                              const u16* __restrict__ C,
                                              const float* __restrict__ bias,
                                              float* __restrict__ y,
                                              int n0) {
  __shared__ u16 lds[2][2][128 * 64];   // [buf][A/B][row*64 + k]  (64 KB)
  int t = threadIdx.x;
  int chunk = gridDim.x >> 3;
  int rb = blockIdx.x;
  int virt = (rb & 7) * chunk + (rb >> 3);
  int q  = virt & 511;
  int n  = n0 + (virt >> 9);
  int o  = q >> 4;
  int lt = (q >> 2) & 3;
  int vt = q & 3;                 // vt fastest: 4 consecutive blocks share B panel
  int v0 = vt << 7, l0 = lt << 7;
  const u16* Cp = C + (size_t)((n - n0) * 32 + o) * (512 * 1536);

  int lane = t & 63, wid = t >> 6;
  int l15 = lane & 15, g = lane >> 4;     // g in 0..3
  int wr = wid >> 1, wc = wid & 1;

  // --- staging addresses (pre-swizzled source; linear LDS dest) ---
  // linear LDS byte L = c*4096 + t*16  ->  row = c*32 + (t>>3), slot = t&7
  // content of (row, slot) must be global slot' = slot ^ (row&7)
  int rowt  = t >> 3;                       // 0..31
  int slotp = (t & 7) ^ (rowt & 7);         // row&7 == (t>>3)&7 for all c
  const u16* gA = G  + (size_t)(v0 + rowt) * 1536 + slotp * 8;
  const u16* gB = Cp + (size_t)(l0 + rowt) * 1536 + slotp * 8;
  char* lA0 = (char*)&lds[0][0][0] + (wid << 10);
  char* lB0 = (char*)&lds[0][1][0] + (wid << 10);
  const int BUFB = 2 * 128 * 64 * 2;        // bytes between buf 0 and buf 1

#define STAGE(b, ks)                                                        \
  do {                                                                      \
    _Pragma("unroll")                                                       \
    for (int cc = 0; cc < 4; ++cc) {                                        \
      gld16(gA + (size_t)cc * 49152 + (ks), lA0 + (b) * BUFB + cc * 4096);  \
      gld16(gB + (size_t)cc * 49152 + (ks), lB0 + (b) * BUFB + cc * 4096);  \
    }                                                                       \
  } while (0)

  // --- fragment read offsets (swizzled) ---
  // frag (16-row block base R0, kk, g): byte = (R0+l15)*128 + ((kk*4+g)^(l15&7))*16
  int sx[2];
  sx[0] = ((g)     ^ (l15 & 7)) << 4;
  sx[1] = ((4 | g) ^ (l15 & 7)) << 4;
  int abase = (wr << 13) + (l15 << 7);      // wr*64 rows * 128B + l15*128B
  int bbase = (wc << 13) + (l15 << 7);

  f32x4 acc[4][4];
#pragma unroll
  for (int i = 0; i < 4; ++i)
#pragma unroll
    for (int j = 0; j < 4; ++j) {
      f32x4 z = {0.f, 0.f, 0.f, 0.f};
      acc[i][j] = z;
    }

  STAGE(0, 0);
  __syncthreads();                          // drains vmcnt(0): tile 0 landed

  for (int tt = 0; tt < 24; ++tt) {
    int b = tt & 1;
    if (tt + 1 < 24) STAGE(b ^ 1, (tt + 1) * 64);   // issue EARLY, wait at barrier
    const char* bufA = (const char*)&lds[b][0][0];
    const char* bufB = (const char*)&lds[b][1][0];
#pragma unroll
    for (int kk = 0; kk < 2; ++kk) {
      bf16x8 af[4], bf[4];
#pragma unroll
      for (int i = 0; i < 4; ++i) {
        af[i] = *(const bf16x8*)(bufA + abase + i * 2048 + sx[kk]);
        bf[i] = *(const bf16x8*)(bufB + bbase + i * 2048 + sx[kk]);
      }
#pragma unroll
      for (int mi = 0; mi < 4; ++mi)
#pragma unroll
        for (int ni = 0; ni < 4; ++ni)
          acc[mi][ni] = __builtin_amdgcn_mfma_f32_16x16x32_bf16(af[mi], bf[ni], acc[mi][ni], 0, 0, 0);
    }
    __syncthreads();   // auto vmcnt(0)+lgkmcnt(0): next tile landed, reads done
  }
#undef STAGE

  float bo = bias[o];
#pragma unroll
  for (int mi = 0; mi < 4; ++mi)
#pragma unroll
    for (int ni = 0; ni < 4; ++ni)
#pragma unroll
      for (int r = 0; r < 4; ++r) {
        int vv = v0 + wr * 64 + mi * 16 + g * 4 + r;
        int ll = l0 + wc * 64 + ni * 16 + l15;
        size_t idx = (((size_t)(n * 32 + o) * 512 + vv) << 9) + ll;
        y[idx] += acc[mi][ni][r] + bo;   // y holds C0 from k_mix
      }
}

// ---------------------------------------------------------------------------
extern "C" void kernel_launch(void* const* d_in, const int* in_sizes, int n_in,
                              void* d_out, int out_size, void* d_ws, size_t ws_size,
                              hipStream_t stream) {
  (void)in_sizes; (void)n_in; (void)out_size;
  const float* x    = (const float*)d_in[0];
  const float* adj  = (const float*)d_in[1];
  const float* W    = (const float*)d_in[2];
  const float* bias = (const float*)d_in[3];
  float* y = (float*)d_out;
  char* ws = (char*)d_ws;

  u16*   G  = (u16*)(ws);                  // 512*1536*2      = 1,572,864
  float* Af = (float*)(ws + 1572864);      // 512*512*4       = 1,048,576
  float* A2 = (float*)(ws + 2621440);      // 512*512*4       = 1,048,576
  u16*   U  = (u16*)(ws + 3670016);        // 128*32*2        = 8,192
  u16*   C  = (u16*)(ws + 3678208);        // per-n: 32*512*1536*2 = 50,331,648
  const size_t fixed = 3678208;
  const size_t per_n = (size_t)32 * 512 * 1536 * 2;

  int grp = 0;
  const int cands[4] = {8, 4, 2, 1};
  for (int i = 0; i < 4; ++i)
    if (fixed + (size_t)cands[i] * per_n <= ws_size) { grp = cands[i]; break; }
  if (!grp) return;

  k_norm<<<dim3(512), dim3(256), 0, stream>>>(adj, Af, G);
  k_pow <<<dim3(128), dim3(256), 0, stream>>>(Af, Af, A2, G, 512);
  k_pow <<<dim3(128), dim3(256), 0, stream>>>(A2, Af, (float*)nullptr, G, 1024);
  k_u   <<<dim3(1),   dim3(128), 0, stream>>>(W, U);

  for (int n0 = 0; n0 < 8; n0 += grp) {
    k_mix <<<dim3(grp * 512), dim3(256), 0, stream>>>(x, U, C, y, n0);
    k_gemm<<<dim3(grp * 512), dim3(256), 0, stream>>>(G, C, bias, y, n0);
  }
}

// Round 3
// 615.147 us; speedup vs baseline: 1.4394x; 1.3406x over previous
//
#include <hip/hip_runtime.h>
#include <cstdint>
#include <cstddef>

typedef unsigned short u16;
typedef unsigned int   u32;
typedef __attribute__((ext_vector_type(8))) short bf16x8;   // 8 bf16 in 4 VGPRs
typedef __attribute__((ext_vector_type(4))) float f32x4;

#define ALPHA 0.05f
#define OMA   0.95f

__device__ __forceinline__ u16 f2b(float f) {
  u32 u = __float_as_uint(f);
  u = (u + 0x7fffu + ((u >> 16) & 1u)) >> 16;   // RNE f32->bf16
  return (u16)u;
}

__device__ __forceinline__ void gld16(const void* g, void* l) {
  __builtin_amdgcn_global_load_lds((const __attribute__((address_space(1))) u32*)g,
                                   (__attribute__((address_space(3))) u32*)l, 16, 0, 0);
}

// ---------------------------------------------------------------------------
// K0: Abar = 0.95 * rownorm(adj + I) -> fp32 Af
// ---------------------------------------------------------------------------
__global__ __launch_bounds__(256) void k_norm(const float* __restrict__ adj,
                                              float* __restrict__ Af) {
  int v = blockIdx.x;      // 512
  int t = threadIdx.x;     // 256
  float a0 = adj[(size_t)v * 512 + t]       + (t == v ? 1.f : 0.f);
  float a1 = adj[(size_t)v * 512 + t + 256] + (t + 256 == v ? 1.f : 0.f);
  float s = a0 + a1;
  for (int off = 32; off; off >>= 1) s += __shfl_down(s, off);
  __shared__ float ws4[4];
  if ((t & 63) == 0) ws4[t >> 6] = s;
  __syncthreads();
  float inv = OMA / (ws4[0] + ws4[1] + ws4[2] + ws4[3]);
  Af[(size_t)v * 512 + t]       = a0 * inv;
  Af[(size_t)v * 512 + t + 256] = a1 * inv;
}

// ---------------------------------------------------------------------------
// K1/K2: P = L @ R (512x512 fp32)
// ---------------------------------------------------------------------------
__global__ __launch_bounds__(256) void k_pow(const float* __restrict__ L,
                                             const float* __restrict__ R,
                                             float* __restrict__ Pf) {
  __shared__ float lrow[4][512];
  int r0 = blockIdx.x * 4;   // 128 blocks
  int t = threadIdx.x;       // 256
  for (int i = t; i < 4 * 512; i += 256)
    lrow[i >> 9][i & 511] = L[(size_t)(r0 + (i >> 9)) * 512 + (i & 511)];
  __syncthreads();
  float acc[4][2] = {};
  for (int k = 0; k < 512; ++k) {
    float rk0 = R[(size_t)k * 512 + t];
    float rk1 = R[(size_t)k * 512 + t + 256];
#pragma unroll
    for (int r = 0; r < 4; ++r) {
      float lv = lrow[r][k];
      acc[r][0] += lv * rk0;
      acc[r][1] += lv * rk1;
    }
  }
  for (int r = 0; r < 4; ++r) {
    Pf[(size_t)(r0 + r) * 512 + t]       = acc[r][0];
    Pf[(size_t)(r0 + r) * 512 + t + 256] = acc[r][1];
  }
}

// ---------------------------------------------------------------------------
// K3: assemble G[v][w*4+jj] = {I, Abar, Abar^2, Abar^3}[v][w]  (bf16, 512x2048)
// ---------------------------------------------------------------------------
__global__ __launch_bounds__(256) void k_pack(const float* __restrict__ A1,
                                              const float* __restrict__ A2,
                                              const float* __restrict__ A3,
                                              u16* __restrict__ G) {
  int v = blockIdx.x;      // 512
  int t = threadIdx.x;     // 256
#pragma unroll
  for (int h = 0; h < 2; ++h) {
    int w = t + h * 256;
    size_t i = (size_t)v * 512 + w;
    u32 lo = (u32)(w == v ? 0x3F80u : 0u) | ((u32)f2b(A1[i]) << 16);
    u32 hi = (u32)f2b(A2[i]) | ((u32)f2b(A3[i]) << 16);
    *(uint2*)(G + (size_t)v * 2048 + w * 4) = make_uint2(lo, hi);
  }
}

// ---------------------------------------------------------------------------
// K4: U[R=o*4+jj][c]  (bf16, 128x32) from W[32][128]
// ---------------------------------------------------------------------------
__global__ void k_u(const float* __restrict__ W, u16* __restrict__ U) {
  int R = threadIdx.x;   // 128
  int o = R >> 2, j = R & 3;
  for (int c = 0; c < 32; ++c) {
    float w0 = W[o * 128 + c];
    float w1 = W[o * 128 + 32 + c];
    float w2 = W[o * 128 + 64 + c];
    float w3 = W[o * 128 + 96 + c];
    float u;
    if (j == 0)      u = w0 + ALPHA * (w1 + w2 + w3);
    else if (j == 1) u = w1 + ALPHA * (w2 + w3);
    else if (j == 2) u = w2 + ALPHA * w3;
    else             u = w3;
    U[R * 32 + c] = f2b(u);
  }
}

// ---------------------------------------------------------------------------
// P1 (k_mix): per (n, 16-v block, 32-l block): C_jj = U_jj @ x via one
// mfma_f32_16x16x32_bf16 per 16x16 tile (K=32 channels). Lane's 4 regs are
// jj=0..3 at fixed (o, w=node, l) -> ONE 8-B store at C[no][l][w*4..w*4+3].
// 16 lanes => 128-B contiguous bursts. No y pass (identity slice handles C0).
// ---------------------------------------------------------------------------
__global__ __launch_bounds__(256) void k_mix(const float* __restrict__ x,
                                             const u16* __restrict__ Uw,
                                             u16* __restrict__ C,
                                             int n0) {
  __shared__ u16 slab[512 * 32];   // [p][c], p = l*16 + v   (32 KB)
  __shared__ u16 Ul[128 * 32];     // [R][c]                 (8 KB)
  int t = threadIdx.x;
  int chunk = gridDim.x >> 3;
  int rb = blockIdx.x;
  int virt = (rb & 7) * chunk + (rb >> 3);
  int q  = virt & 511;
  int n  = n0 + (virt >> 9);
  int v0 = (q & 31) << 4;    // v-block of 16
  int l0 = (q >> 5) << 5;    // l-block of 32

  gld16(Uw + t * 8,        (char*)Ul + ((t >> 6) << 10));
  gld16(Uw + 2048 + t * 8, (char*)Ul + 4096 + ((t >> 6) << 10));

  int c = t & 31;
  int v = t >> 5;   // 0..7
#pragma unroll
  for (int h = 0; h < 2; ++h) {
    int vv = v + h * 8;
    const float* xp = x + (((size_t)(n * 32 + c) * 512 + v0 + vv) << 9) + l0;
#pragma unroll
    for (int f = 0; f < 8; ++f) {
      float4 d = *(const float4*)(xp + f * 4);
      int p = (f * 4) * 16 + vv;       // p = l*16 + v
      slab[(p + 0)  * 32 + c] = f2b(d.x);
      slab[(p + 16) * 32 + c] = f2b(d.y);
      slab[(p + 32) * 32 + c] = f2b(d.z);
      slab[(p + 48) * 32 + c] = f2b(d.w);
    }
  }
  __syncthreads();

  int lane = t & 63, wid = t >> 6;
  int l15 = lane & 15, g = lane >> 4;

  bf16x8 a[8], b[8];
#pragma unroll
  for (int mt = 0; mt < 8; ++mt)
    a[mt] = *(const bf16x8*)(Ul + (mt * 16 + l15) * 32 + g * 8);
#pragma unroll
  for (int i = 0; i < 8; ++i) {
    int p = (wid * 8 + i) * 16 + l15;
    b[i] = *(const bf16x8*)(slab + p * 32 + g * 8);
  }

  int nol_base = (n - n0) * 32;
  int w = v0 + l15;                    // node index
#pragma unroll
  for (int mt = 0; mt < 8; ++mt) {
    int o = mt * 4 + g;                // D row R = mt*16 + g*4 + reg; jj = reg
    u16* cbase = C + ((size_t)(nol_base + o) * 512 + l0) * 2048 + (size_t)w * 4;
#pragma unroll
    for (int i = 0; i < 8; ++i) {
      f32x4 z = {0.f, 0.f, 0.f, 0.f};
      f32x4 acc = __builtin_amdgcn_mfma_f32_16x16x32_bf16(a[mt], b[i], z, 0, 0, 0);
      int nt = wid * 8 + i;            // l within block
      u32 lo = (u32)f2b(acc[0]) | ((u32)f2b(acc[1]) << 16);
      u32 hi = (u32)f2b(acc[2]) | ((u32)f2b(acc[3]) << 16);
      *(uint2*)(cbase + (size_t)nt * 2048) = make_uint2(lo, hi);
    }
  }
}

// ---------------------------------------------------------------------------
// P2 (k_gemm): per (n,o): y[512,512] = G[512,2048] @ C[no][*,2048]^T + b.
// 128x128 tile, BK=64, 2-phase pipeline, XOR-swizzled LDS (both-sides).
// K=2048 (jj=0 identity slice supplies the C0 term); plain store epilogue.
// ---------------------------------------------------------------------------
__global__ __launch_bounds__(256) void k_gemm(const u16* __restrict__ G,
                                              const u16* __restrict__ C,
                                              const float* __restrict__ bias,
                                              float* __restrict__ y,
                                              int n0) {
  __shared__ u16 lds[2][2][128 * 64];   // [buf][A/B][row*64 + k]  (64 KB)
  int t = threadIdx.x;
  int chunk = gridDim.x >> 3;
  int rb = blockIdx.x;
  int virt = (rb & 7) * chunk + (rb >> 3);
  int q  = virt & 511;
  int n  = n0 + (virt >> 9);
  int o  = q >> 4;
  int lt = (q >> 2) & 3;
  int vt = q & 3;                 // vt fastest: 4 consecutive blocks share B panel
  int v0 = vt << 7, l0 = lt << 7;
  const u16* Cp = C + (size_t)((n - n0) * 32 + o) * (512 * 2048);

  int lane = t & 63, wid = t >> 6;
  int l15 = lane & 15, g = lane >> 4;     // g in 0..3
  int wr = wid >> 1, wc = wid & 1;

  // staging: linear LDS dest (base + lane*16), pre-swizzled global source
  int rowt  = t >> 3;                       // 0..31
  int slotp = (t & 7) ^ (rowt & 7);
  const u16* gA = G  + (size_t)(v0 + rowt) * 2048 + slotp * 8;
  const u16* gB = Cp + (size_t)(l0 + rowt) * 2048 + slotp * 8;
  char* lA0 = (char*)&lds[0][0][0] + (wid << 10);
  char* lB0 = (char*)&lds[0][1][0] + (wid << 10);
  const int BUFB = 2 * 128 * 64 * 2;        // bytes between buf 0 and buf 1

#define STAGE(b, koff)                                                        \
  do {                                                                        \
    _Pragma("unroll")                                                         \
    for (int cc = 0; cc < 4; ++cc) {                                          \
      gld16(gA + (size_t)cc * 65536 + (koff), lA0 + (b) * BUFB + cc * 4096);  \
      gld16(gB + (size_t)cc * 65536 + (koff), lB0 + (b) * BUFB + cc * 4096);  \
    }                                                                         \
  } while (0)

  // swizzled fragment read offsets
  int sx[2];
  sx[0] = ((g)     ^ (l15 & 7)) << 4;
  sx[1] = ((4 | g) ^ (l15 & 7)) << 4;
  int abase = (wr << 13) + (l15 << 7);
  int bbase = (wc << 13) + (l15 << 7);

  f32x4 acc[4][4];
#pragma unroll
  for (int i = 0; i < 4; ++i)
#pragma unroll
    for (int j = 0; j < 4; ++j) {
      f32x4 z = {0.f, 0.f, 0.f, 0.f};
      acc[i][j] = z;
    }

  STAGE(0, 0);
  __syncthreads();

  for (int tt = 0; tt < 32; ++tt) {
    int b = tt & 1;
    if (tt + 1 < 32) STAGE(b ^ 1, (tt + 1) * 64);   // issue early, wait at barrier
    const char* bufA = (const char*)&lds[b][0][0];
    const char* bufB = (const char*)&lds[b][1][0];
#pragma unroll
    for (int kk = 0; kk < 2; ++kk) {
      bf16x8 af[4], bf[4];
#pragma unroll
      for (int i = 0; i < 4; ++i) {
        af[i] = *(const bf16x8*)(bufA + abase + i * 2048 + sx[kk]);
        bf[i] = *(const bf16x8*)(bufB + bbase + i * 2048 + sx[kk]);
      }
#pragma unroll
      for (int mi = 0; mi < 4; ++mi)
#pragma unroll
        for (int ni = 0; ni < 4; ++ni)
          acc[mi][ni] = __builtin_amdgcn_mfma_f32_16x16x32_bf16(af[mi], bf[ni], acc[mi][ni], 0, 0, 0);
    }
    __syncthreads();
  }
#undef STAGE

  float bo = bias[o];
#pragma unroll
  for (int mi = 0; mi < 4; ++mi)
#pragma unroll
    for (int ni = 0; ni < 4; ++ni)
#pragma unroll
      for (int r = 0; r < 4; ++r) {
        int vv = v0 + wr * 64 + mi * 16 + g * 4 + r;
        int ll = l0 + wc * 64 + ni * 16 + l15;
        size_t idx = (((size_t)(n * 32 + o) * 512 + vv) << 9) + ll;
        y[idx] = acc[mi][ni][r] + bo;
      }
}

// ---------------------------------------------------------------------------
extern "C" void kernel_launch(void* const* d_in, const int* in_sizes, int n_in,
                              void* d_out, int out_size, void* d_ws, size_t ws_size,
                              hipStream_t stream) {
  (void)in_sizes; (void)n_in; (void)out_size;
  const float* x    = (const float*)d_in[0];
  const float* adj  = (const float*)d_in[1];
  const float* W    = (const float*)d_in[2];
  const float* bias = (const float*)d_in[3];
  float* y = (float*)d_out;
  char* ws = (char*)d_ws;

  u16*   G  = (u16*)(ws);                  // 512*2048*2      = 2,097,152
  float* Af = (float*)(ws + 2097152);      // 512*512*4       = 1,048,576
  float* A2 = (float*)(ws + 3145728);      // 1,048,576
  float* A3 = (float*)(ws + 4194304);      // 1,048,576
  u16*   U  = (u16*)(ws + 5242880);        // 128*32*2        = 8,192
  u16*   C  = (u16*)(ws + 5251072);        // per-n: 32*512*2048*2 = 67,108,864
  const size_t fixed = 5251072;
  const size_t per_n = (size_t)32 * 512 * 2048 * 2;

  int grp = 0;
  const int cands[4] = {8, 4, 2, 1};
  for (int i = 0; i < 4; ++i)
    if (fixed + (size_t)cands[i] * per_n <= ws_size) { grp = cands[i]; break; }
  if (!grp) return;

  k_norm<<<dim3(512), dim3(256), 0, stream>>>(adj, Af);
  k_pow <<<dim3(128), dim3(256), 0, stream>>>(Af, Af, A2);
  k_pow <<<dim3(128), dim3(256), 0, stream>>>(A2, Af, A3);
  k_pack<<<dim3(512), dim3(256), 0, stream>>>(Af, A2, A3, G);
  k_u   <<<dim3(1),   dim3(128), 0, stream>>>(W, U);

  for (int n0 = 0; n0 < 8; n0 += grp) {
    k_mix <<<dim3(grp * 512), dim3(256), 0, stream>>>(x, U, C, n0);
    k_gemm<<<dim3(grp * 512), dim3(256), 0, stream>>>(G, C, bias, y, n0);
  }
}

// Round 5
// 495.032 us; speedup vs baseline: 1.7886x; 1.2426x over previous
//
#include <hip/hip_runtime.h>
#include <cstdint>
#include <cstddef>

typedef unsigned short u16;
typedef unsigned int   u32;
typedef __attribute__((ext_vector_type(8))) short bf16x8;   // 8 bf16 in 4 VGPRs
typedef __attribute__((ext_vector_type(4))) float f32x4;

#define ALPHA 0.05f
#define OMA   0.95f

__device__ __forceinline__ u16 f2b(float f) {
  u32 u = __float_as_uint(f);
  u = (u + 0x7fffu + ((u >> 16) & 1u)) >> 16;   // RNE f32->bf16
  return (u16)u;
}

__device__ __forceinline__ void gld16(const void* g, void* l) {
  __builtin_amdgcn_global_load_lds((const __attribute__((address_space(1))) u32*)g,
                                   (__attribute__((address_space(3))) u32*)l, 16, 0, 0);
}

// ---------------------------------------------------------------------------
// K0: Abar = 0.95 * rownorm(adj + I) -> fp32 Af
// ---------------------------------------------------------------------------
__global__ __launch_bounds__(256) void k_norm(const float* __restrict__ adj,
                                              float* __restrict__ Af) {
  int v = blockIdx.x;      // 512
  int t = threadIdx.x;     // 256
  float a0 = adj[(size_t)v * 512 + t]       + (t == v ? 1.f : 0.f);
  float a1 = adj[(size_t)v * 512 + t + 256] + (t + 256 == v ? 1.f : 0.f);
  float s = a0 + a1;
  for (int off = 32; off; off >>= 1) s += __shfl_down(s, off);
  __shared__ float ws4[4];
  if ((t & 63) == 0) ws4[t >> 6] = s;
  __syncthreads();
  float inv = OMA / (ws4[0] + ws4[1] + ws4[2] + ws4[3]);
  Af[(size_t)v * 512 + t]       = a0 * inv;
  Af[(size_t)v * 512 + t + 256] = a1 * inv;
}

// ---------------------------------------------------------------------------
// K1/K2: P = L @ R (512x512 fp32)
// ---------------------------------------------------------------------------
__global__ __launch_bounds__(256) void k_pow(const float* __restrict__ L,
                                             const float* __restrict__ R,
                                             float* __restrict__ Pf) {
  __shared__ float lrow[4][512];
  int r0 = blockIdx.x * 4;   // 128 blocks
  int t = threadIdx.x;       // 256
  for (int i = t; i < 4 * 512; i += 256)
    lrow[i >> 9][i & 511] = L[(size_t)(r0 + (i >> 9)) * 512 + (i & 511)];
  __syncthreads();
  float acc[4][2] = {};
  for (int k = 0; k < 512; ++k) {
    float rk0 = R[(size_t)k * 512 + t];
    float rk1 = R[(size_t)k * 512 + t + 256];
#pragma unroll
    for (int r = 0; r < 4; ++r) {
      float lv = lrow[r][k];
      acc[r][0] += lv * rk0;
      acc[r][1] += lv * rk1;
    }
  }
  for (int r = 0; r < 4; ++r) {
    Pf[(size_t)(r0 + r) * 512 + t]       = acc[r][0];
    Pf[(size_t)(r0 + r) * 512 + t + 256] = acc[r][1];
  }
}

// ---------------------------------------------------------------------------
// K3: assemble G[v][w*4+jj] = {I, Abar, Abar^2, Abar^3}[v][w]  (bf16, 512x2048)
// ---------------------------------------------------------------------------
__global__ __launch_bounds__(256) void k_pack(const float* __restrict__ A1,
                                              const float* __restrict__ A2,
                                              const float* __restrict__ A3,
                                              u16* __restrict__ G) {
  int v = blockIdx.x;      // 512
  int t = threadIdx.x;     // 256
#pragma unroll
  for (int h = 0; h < 2; ++h) {
    int w = t + h * 256;
    size_t i = (size_t)v * 512 + w;
    u32 lo = (u32)(w == v ? 0x3F80u : 0u) | ((u32)f2b(A1[i]) << 16);
    u32 hi = (u32)f2b(A2[i]) | ((u32)f2b(A3[i]) << 16);
    *(uint2*)(G + (size_t)v * 2048 + w * 4) = make_uint2(lo, hi);
  }
}

// ---------------------------------------------------------------------------
// K4: U[R=o*4+jj][c]  (bf16, 128x32) from W[32][128]
// ---------------------------------------------------------------------------
__global__ void k_u(const float* __restrict__ W, u16* __restrict__ U) {
  int R = threadIdx.x;   // 128
  int o = R >> 2, j = R & 3;
  for (int c = 0; c < 32; ++c) {
    float w0 = W[o * 128 + c];
    float w1 = W[o * 128 + 32 + c];
    float w2 = W[o * 128 + 64 + c];
    float w3 = W[o * 128 + 96 + c];
    float u;
    if (j == 0)      u = w0 + ALPHA * (w1 + w2 + w3);
    else if (j == 1) u = w1 + ALPHA * (w2 + w3);
    else if (j == 2) u = w2 + ALPHA * w3;
    else             u = w3;
    U[R * 32 + c] = f2b(u);
  }
}

// ---------------------------------------------------------------------------
// P1 (k_mix): C_jj = U_jj @ x; lane's 4 regs (jj=0..3) -> one 8-B store.
// ---------------------------------------------------------------------------
__global__ __launch_bounds__(256) void k_mix(const float* __restrict__ x,
                                             const u16* __restrict__ Uw,
                                             u16* __restrict__ C,
                                             int n0) {
  __shared__ u16 slab[512 * 32];   // [p][c], p = l*16 + v   (32 KB)
  __shared__ u16 Ul[128 * 32];     // [R][c]                 (8 KB)
  int t = threadIdx.x;
  int chunk = gridDim.x >> 3;
  int rb = blockIdx.x;
  int virt = (rb & 7) * chunk + (rb >> 3);
  int q  = virt & 511;
  int n  = n0 + (virt >> 9);
  int v0 = (q & 31) << 4;    // v-block of 16
  int l0 = (q >> 5) << 5;    // l-block of 32

  gld16(Uw + t * 8,        (char*)Ul + ((t >> 6) << 10));
  gld16(Uw + 2048 + t * 8, (char*)Ul + 4096 + ((t >> 6) << 10));

  int c = t & 31;
  int v = t >> 5;   // 0..7
#pragma unroll
  for (int h = 0; h < 2; ++h) {
    int vv = v + h * 8;
    const float* xp = x + (((size_t)(n * 32 + c) * 512 + v0 + vv) << 9) + l0;
#pragma unroll
    for (int f = 0; f < 8; ++f) {
      float4 d = *(const float4*)(xp + f * 4);
      int p = (f * 4) * 16 + vv;       // p = l*16 + v
      slab[(p + 0)  * 32 + c] = f2b(d.x);
      slab[(p + 16) * 32 + c] = f2b(d.y);
      slab[(p + 32) * 32 + c] = f2b(d.z);
      slab[(p + 48) * 32 + c] = f2b(d.w);
    }
  }
  __syncthreads();

  int lane = t & 63, wid = t >> 6;
  int l15 = lane & 15, g = lane >> 4;

  bf16x8 a[8], b[8];
#pragma unroll
  for (int mt = 0; mt < 8; ++mt)
    a[mt] = *(const bf16x8*)(Ul + (mt * 16 + l15) * 32 + g * 8);
#pragma unroll
  for (int i = 0; i < 8; ++i) {
    int p = (wid * 8 + i) * 16 + l15;
    b[i] = *(const bf16x8*)(slab + p * 32 + g * 8);
  }

  int nol_base = (n - n0) * 32;
  int w = v0 + l15;                    // node index
#pragma unroll
  for (int mt = 0; mt < 8; ++mt) {
    int o = mt * 4 + g;                // D row R = mt*16 + g*4 + reg; jj = reg
    u16* cbase = C + ((size_t)(nol_base + o) * 512 + l0) * 2048 + (size_t)w * 4;
#pragma unroll
    for (int i = 0; i < 8; ++i) {
      f32x4 z = {0.f, 0.f, 0.f, 0.f};
      f32x4 acc = __builtin_amdgcn_mfma_f32_16x16x32_bf16(a[mt], b[i], z, 0, 0, 0);
      int nt = wid * 8 + i;            // l within block
      u32 lo = (u32)f2b(acc[0]) | ((u32)f2b(acc[1]) << 16);
      u32 hi = (u32)f2b(acc[2]) | ((u32)f2b(acc[3]) << 16);
      *(uint2*)(cbase + (size_t)nt * 2048) = make_uint2(lo, hi);
    }
  }
}

// ---------------------------------------------------------------------------
// P2 (k_gemm): per (n,o): y[512,512] = G[512,2048] @ C[no][*,2048]^T + b.
// 256x256 tile, BK=64, 8-phase counted-vmcnt pipeline (T2+T3+T4+T5).
// 8 waves (2Mx4N), 128 KiB LDS double-buffer, vmcnt(6) at phases 4/8.
// FIX vs R4: LAST iteration's ph4 drains vmcnt(0) — with no T2 staging, only
// 8 loads are outstanding there and vmcnt(6) left t1's {Ah1,Bh0,Bh1} unlanded
// before ph5's RDALL(1) (the R4 absmax=0.77 race).
// ---------------------------------------------------------------------------
#define BAR   asm volatile("s_barrier" ::: "memory")
#define LGKM0 do { asm volatile("s_waitcnt lgkmcnt(0)" ::: "memory");          \
                   __builtin_amdgcn_sched_barrier(0); } while (0)
#define VM6   asm volatile("s_waitcnt vmcnt(6)" ::: "memory")
#define VM0   asm volatile("s_waitcnt vmcnt(0)" ::: "memory")

__global__ __launch_bounds__(512, 2) void k_gemm(const u16* __restrict__ G,
                                                 const u16* __restrict__ C,
                                                 const float* __restrict__ bias,
                                                 float* __restrict__ y,
                                                 int n0) {
  __shared__ u16 lds[65536];   // 128 KB. Bytes: A(b)=b*32768, B(b)=65536+b*32768
  int t = threadIdx.x;
  int rb = blockIdx.x;
  int chunk = gridDim.x >> 3;
  int virt = (rb & 7) * chunk + (rb >> 3);
  int nn = n0 + (virt >> 7);
  int r7 = virt & 127;
  int o  = r7 >> 2;
  int vt = (r7 >> 1) & 1, lt = r7 & 1;
  int v0 = vt << 8, l0 = lt << 8;
  const u16* Cp = C + (size_t)((nn - n0) * 32 + o) * (512 * 2048);

  int lane = t & 63, wid = t >> 6;
  int l15 = lane & 15, g = lane >> 4;
  int wm = wid >> 2, wn = wid & 3;          // 2M x 4N wave grid

  // staging source (pre-swizzled slot), linear LDS dest
  int rr = t >> 3;                          // 0..63
  int sp = (t & 7) ^ (rr & 7);
  const u16* gA = G  + (size_t)(v0 + rr) * 2048 + sp * 8;
  const u16* gB = Cp + (size_t)(l0 + rr) * 2048 + sp * 8;
  char* ldsw = (char*)lds + (wid << 10);

#define STGA(b, T, h)                                                        \
  do {                                                                       \
    const u16* s_ = gA + (size_t)(h) * 262144 + (size_t)(T) * 64;            \
    gld16(s_,          ldsw + (b) * 32768 + (h) * 16384);                    \
    gld16(s_ + 131072, ldsw + (b) * 32768 + (h) * 16384 + 8192);             \
  } while (0)
#define STGB(b, T, h)                                                        \
  do {                                                                       \
    const u16* s_ = gB + (size_t)(h) * 262144 + (size_t)(T) * 64;            \
    gld16(s_,          ldsw + 65536 + (b) * 32768 + (h) * 16384);            \
    gld16(s_ + 131072, ldsw + 65536 + (b) * 32768 + (h) * 16384 + 8192);     \
  } while (0)

  // swizzled fragment read offsets
  int sx0 = (g ^ (l15 & 7)) << 4;
  int sx1 = ((4 | g) ^ (l15 & 7)) << 4;
  int aoff = (wm * 128 + l15) * 128;        // bytes
  int boff = (wn * 64 + l15) * 128;
  const char* ldsc = (const char*)lds;

  bf16x8 af[8][2], bf[4][2];
#define RDALL(b)                                                             \
  do {                                                                       \
    _Pragma("unroll") for (int m = 0; m < 8; ++m) {                          \
      af[m][0] = *(const bf16x8*)(ldsc + (b) * 32768 + aoff + m * 2048 + sx0); \
      af[m][1] = *(const bf16x8*)(ldsc + (b) * 32768 + aoff + m * 2048 + sx1); \
    }                                                                        \
    _Pragma("unroll") for (int n = 0; n < 4; ++n) {                          \
      bf[n][0] = *(const bf16x8*)(ldsc + 65536 + (b) * 32768 + boff + n * 2048 + sx0); \
      bf[n][1] = *(const bf16x8*)(ldsc + 65536 + (b) * 32768 + boff + n * 2048 + sx1); \
    }                                                                        \
  } while (0)

  f32x4 acc[8][4];
#pragma unroll
  for (int i = 0; i < 8; ++i)
#pragma unroll
    for (int j = 0; j < 4; ++j) {
      f32x4 z = {0.f, 0.f, 0.f, 0.f};
      acc[i][j] = z;
    }

#define CLUSTER(mh, ks)                                                      \
  do {                                                                       \
    __builtin_amdgcn_s_setprio(1);                                           \
    _Pragma("unroll") for (int m = 0; m < 4; ++m)                            \
    _Pragma("unroll") for (int n = 0; n < 4; ++n)                            \
      acc[(mh) * 4 + m][n] = __builtin_amdgcn_mfma_f32_16x16x32_bf16(        \
          af[(mh) * 4 + m][ks], bf[n][ks], acc[(mh) * 4 + m][n], 0, 0, 0);   \
    __builtin_amdgcn_s_setprio(0);                                           \
  } while (0)

  // prologue: tile0 (buf0) full + tile1 (buf1) Ah0,Ah1,Bh0  (7 half-tiles)
  STGA(0, 0, 0); STGA(0, 0, 1); STGB(0, 0, 0); STGB(0, 0, 1);
  STGA(1, 1, 0); STGA(1, 1, 1); STGB(1, 1, 0);
  VM6;            // newest 6 loads = tile1's 3 halves -> tile0 fully landed
  BAR;

  for (int tt = 0; tt < 16; ++tt) {
    int t1 = 2 * tt + 1;
    int T2 = 2 * tt + 2;     // next buf0 tile
    int T3 = 2 * tt + 3;     // next buf1 tile
    bool more = (tt < 15);
    // ph1
    RDALL(0);
    STGB(1, t1, 1);          // t1's 4th half (B h1)
    BAR; LGKM0;
    CLUSTER(0, 0); BAR;
    // ph2
    if (more) STGA(0, T2, 0);
    BAR; CLUSTER(0, 1); BAR;
    // ph3
    if (more) STGA(0, T2, 1);
    BAR; CLUSTER(1, 0); BAR;
    // ph4
    if (more) {
      STGB(0, T2, 0);
      VM6;                   // newest 6 = T2.Ah0,Ah1,Bh0 -> t1 fully landed
    } else {
      VM0;                   // tail: only 8 outstanding; drain so t1 lands
    }
    BAR; CLUSTER(1, 1); BAR;
    // ph5
    RDALL(1);
    if (more) STGB(0, T2, 1);
    BAR; LGKM0;
    CLUSTER(0, 0); BAR;
    // ph6
    if (more) STGA(1, T3, 0);
    BAR; CLUSTER(0, 1); BAR;
    // ph7
    if (more) STGA(1, T3, 1);
    BAR; CLUSTER(1, 0); BAR;
    // ph8
    if (more) {
      STGB(1, T3, 0);
      VM6;                   // newest 6 = T3.Ah0,Ah1,Bh0 -> T2 fully landed
    }
    BAR; CLUSTER(1, 1); BAR;
  }
#undef STGA
#undef STGB
#undef RDALL
#undef CLUSTER

  float bo = bias[o];
#pragma unroll
  for (int mm = 0; mm < 8; ++mm)
#pragma unroll
    for (int n = 0; n < 4; ++n)
#pragma unroll
      for (int q = 0; q < 4; ++q) {
        int vv = v0 + wm * 128 + mm * 16 + g * 4 + q;
        int ll = l0 + wn * 64 + n * 16 + l15;
        size_t idx = (((size_t)(nn * 32 + o) * 512 + vv) << 9) + ll;
        y[idx] = acc[mm][n][q] + bo;
      }
}

// ---------------------------------------------------------------------------
extern "C" void kernel_launch(void* const* d_in, const int* in_sizes, int n_in,
                              void* d_out, int out_size, void* d_ws, size_t ws_size,
                              hipStream_t stream) {
  (void)in_sizes; (void)n_in; (void)out_size;
  const float* x    = (const float*)d_in[0];
  const float* adj  = (const float*)d_in[1];
  const float* W    = (const float*)d_in[2];
  const float* bias = (const float*)d_in[3];
  float* y = (float*)d_out;
  char* ws = (char*)d_ws;

  u16*   G  = (u16*)(ws);                  // 512*2048*2      = 2,097,152
  float* Af = (float*)(ws + 2097152);      // 512*512*4       = 1,048,576
  float* A2 = (float*)(ws + 3145728);      // 1,048,576
  float* A3 = (float*)(ws + 4194304);      // 1,048,576
  u16*   U  = (u16*)(ws + 5242880);        // 128*32*2        = 8,192
  u16*   C  = (u16*)(ws + 5251072);        // per-n: 32*512*2048*2 = 67,108,864
  const size_t fixed = 5251072;
  const size_t per_n = (size_t)32 * 512 * 2048 * 2;

  int grp = 0;
  const int cands[4] = {8, 4, 2, 1};
  for (int i = 0; i < 4; ++i)
    if (fixed + (size_t)cands[i] * per_n <= ws_size) { grp = cands[i]; break; }
  if (!grp) return;

  k_norm<<<dim3(512), dim3(256), 0, stream>>>(adj, Af);
  k_pow <<<dim3(128), dim3(256), 0, stream>>>(Af, Af, A2);
  k_pow <<<dim3(128), dim3(256), 0, stream>>>(A2, Af, A3);
  k_pack<<<dim3(512), dim3(256), 0, stream>>>(Af, A2, A3, G);
  k_u   <<<dim3(1),   dim3(128), 0, stream>>>(W, U);

  for (int n0 = 0; n0 < 8; n0 += grp) {
    k_mix <<<dim3(grp * 512), dim3(256), 0, stream>>>(x, U, C, n0);
    k_gemm<<<dim3(grp * 128), dim3(512), 0, stream>>>(G, C, bias, y, n0);
  }
}

// Round 6
// 493.246 us; speedup vs baseline: 1.7951x; 1.0036x over previous
//
#include <hip/hip_runtime.h>
#include <cstdint>
#include <cstddef>

typedef unsigned short u16;
typedef unsigned int   u32;
typedef __attribute__((ext_vector_type(8))) short bf16x8;   // 8 bf16 in 4 VGPRs
typedef __attribute__((ext_vector_type(4))) float f32x4;

#define ALPHA 0.05f
#define OMA   0.95f

__device__ __forceinline__ u16 f2b(float f) {
  u32 u = __float_as_uint(f);
  u = (u + 0x7fffu + ((u >> 16) & 1u)) >> 16;   // RNE f32->bf16
  return (u16)u;
}

__device__ __forceinline__ void gld16(const void* g, void* l) {
  __builtin_amdgcn_global_load_lds((const __attribute__((address_space(1))) u32*)g,
                                   (__attribute__((address_space(3))) u32*)l, 16, 0, 0);
}

// ---------------------------------------------------------------------------
// K0: Abar = 0.95 * rownorm(adj + I) -> fp32 Af
// ---------------------------------------------------------------------------
__global__ __launch_bounds__(256) void k_norm(const float* __restrict__ adj,
                                              float* __restrict__ Af) {
  int v = blockIdx.x;      // 512
  int t = threadIdx.x;     // 256
  float a0 = adj[(size_t)v * 512 + t]       + (t == v ? 1.f : 0.f);
  float a1 = adj[(size_t)v * 512 + t + 256] + (t + 256 == v ? 1.f : 0.f);
  float s = a0 + a1;
  for (int off = 32; off; off >>= 1) s += __shfl_down(s, off);
  __shared__ float ws4[4];
  if ((t & 63) == 0) ws4[t >> 6] = s;
  __syncthreads();
  float inv = OMA / (ws4[0] + ws4[1] + ws4[2] + ws4[3]);
  Af[(size_t)v * 512 + t]       = a0 * inv;
  Af[(size_t)v * 512 + t + 256] = a1 * inv;
}

// ---------------------------------------------------------------------------
// K1/K2: P = L @ R (512x512 fp32)
// ---------------------------------------------------------------------------
__global__ __launch_bounds__(256) void k_pow(const float* __restrict__ L,
                                             const float* __restrict__ R,
                                             float* __restrict__ Pf) {
  __shared__ float lrow[4][512];
  int r0 = blockIdx.x * 4;   // 128 blocks
  int t = threadIdx.x;       // 256
  for (int i = t; i < 4 * 512; i += 256)
    lrow[i >> 9][i & 511] = L[(size_t)(r0 + (i >> 9)) * 512 + (i & 511)];
  __syncthreads();
  float acc[4][2] = {};
  for (int k = 0; k < 512; ++k) {
    float rk0 = R[(size_t)k * 512 + t];
    float rk1 = R[(size_t)k * 512 + t + 256];
#pragma unroll
    for (int r = 0; r < 4; ++r) {
      float lv = lrow[r][k];
      acc[r][0] += lv * rk0;
      acc[r][1] += lv * rk1;
    }
  }
  for (int r = 0; r < 4; ++r) {
    Pf[(size_t)(r0 + r) * 512 + t]       = acc[r][0];
    Pf[(size_t)(r0 + r) * 512 + t + 256] = acc[r][1];
  }
}

// ---------------------------------------------------------------------------
// K3: assemble G[v][w*4+jj] = {I, Abar, Abar^2, Abar^3}[v][w]  (bf16, 512x2048)
// ---------------------------------------------------------------------------
__global__ __launch_bounds__(256) void k_pack(const float* __restrict__ A1,
                                              const float* __restrict__ A2,
                                              const float* __restrict__ A3,
                                              u16* __restrict__ G) {
  int v = blockIdx.x;      // 512
  int t = threadIdx.x;     // 256
#pragma unroll
  for (int h = 0; h < 2; ++h) {
    int w = t + h * 256;
    size_t i = (size_t)v * 512 + w;
    u32 lo = (u32)(w == v ? 0x3F80u : 0u) | ((u32)f2b(A1[i]) << 16);
    u32 hi = (u32)f2b(A2[i]) | ((u32)f2b(A3[i]) << 16);
    *(uint2*)(G + (size_t)v * 2048 + w * 4) = make_uint2(lo, hi);
  }
}

// ---------------------------------------------------------------------------
// K4: U[R=o*4+jj][c]  (bf16, 128x32) from W[32][128]
// ---------------------------------------------------------------------------
__global__ void k_u(const float* __restrict__ W, u16* __restrict__ U) {
  int R = threadIdx.x;   // 128
  int o = R >> 2, j = R & 3;
  for (int c = 0; c < 32; ++c) {
    float w0 = W[o * 128 + c];
    float w1 = W[o * 128 + 32 + c];
    float w2 = W[o * 128 + 64 + c];
    float w3 = W[o * 128 + 96 + c];
    float u;
    if (j == 0)      u = w0 + ALPHA * (w1 + w2 + w3);
    else if (j == 1) u = w1 + ALPHA * (w2 + w3);
    else if (j == 2) u = w2 + ALPHA * w3;
    else             u = w3;
    U[R * 32 + c] = f2b(u);
  }
}

// ---------------------------------------------------------------------------
// P1 (k_mix): C_jj = U_jj @ x; lane's 4 regs (jj=0..3) -> one 8-B store.
// ---------------------------------------------------------------------------
__global__ __launch_bounds__(256) void k_mix(const float* __restrict__ x,
                                             const u16* __restrict__ Uw,
                                             u16* __restrict__ C,
                                             int n0) {
  __shared__ u16 slab[512 * 32];   // [p][c], p = l*16 + v   (32 KB)
  __shared__ u16 Ul[128 * 32];     // [R][c]                 (8 KB)
  int t = threadIdx.x;
  int chunk = gridDim.x >> 3;
  int rb = blockIdx.x;
  int virt = (rb & 7) * chunk + (rb >> 3);
  int q  = virt & 511;
  int n  = n0 + (virt >> 9);
  int v0 = (q & 31) << 4;    // v-block of 16
  int l0 = (q >> 5) << 5;    // l-block of 32

  gld16(Uw + t * 8,        (char*)Ul + ((t >> 6) << 10));
  gld16(Uw + 2048 + t * 8, (char*)Ul + 4096 + ((t >> 6) << 10));

  int c = t & 31;
  int v = t >> 5;   // 0..7
#pragma unroll
  for (int h = 0; h < 2; ++h) {
    int vv = v + h * 8;
    const float* xp = x + (((size_t)(n * 32 + c) * 512 + v0 + vv) << 9) + l0;
#pragma unroll
    for (int f = 0; f < 8; ++f) {
      float4 d = *(const float4*)(xp + f * 4);
      int p = (f * 4) * 16 + vv;       // p = l*16 + v
      slab[(p + 0)  * 32 + c] = f2b(d.x);
      slab[(p + 16) * 32 + c] = f2b(d.y);
      slab[(p + 32) * 32 + c] = f2b(d.z);
      slab[(p + 48) * 32 + c] = f2b(d.w);
    }
  }
  __syncthreads();

  int lane = t & 63, wid = t >> 6;
  int l15 = lane & 15, g = lane >> 4;

  bf16x8 a[8], b[8];
#pragma unroll
  for (int mt = 0; mt < 8; ++mt)
    a[mt] = *(const bf16x8*)(Ul + (mt * 16 + l15) * 32 + g * 8);
#pragma unroll
  for (int i = 0; i < 8; ++i) {
    int p = (wid * 8 + i) * 16 + l15;
    b[i] = *(const bf16x8*)(slab + p * 32 + g * 8);
  }

  int nol_base = (n - n0) * 32;
  int w = v0 + l15;                    // node index
#pragma unroll
  for (int mt = 0; mt < 8; ++mt) {
    int o = mt * 4 + g;                // D row R = mt*16 + g*4 + reg; jj = reg
    u16* cbase = C + ((size_t)(nol_base + o) * 512 + l0) * 2048 + (size_t)w * 4;
#pragma unroll
    for (int i = 0; i < 8; ++i) {
      f32x4 z = {0.f, 0.f, 0.f, 0.f};
      f32x4 acc = __builtin_amdgcn_mfma_f32_16x16x32_bf16(a[mt], b[i], z, 0, 0, 0);
      int nt = wid * 8 + i;            // l within block
      u32 lo = (u32)f2b(acc[0]) | ((u32)f2b(acc[1]) << 16);
      u32 hi = (u32)f2b(acc[2]) | ((u32)f2b(acc[3]) << 16);
      *(uint2*)(cbase + (size_t)nt * 2048) = make_uint2(lo, hi);
    }
  }
}

// ---------------------------------------------------------------------------
// P2 (k_gemm): per (n,o): y[512,512] = G[512,2048] @ C[no][*,2048]^T + b.
// 256x256 tile, BK=64, 8-phase counted-vmcnt pipeline (T2+T3+T4+T5).
// R5->R6: ds_reads split per-phase (ph1: k0 set, ph2: k1 set) instead of a
// 24-read burst + lgkmcnt(0); staging re-slotted 1 half/phase
// (ph1,2: t1.B | ph3,4: T2.A | ph5,6: T2.B | ph7,8: T3.A); vmcnt(4) at
// ph4/ph8 (12 outstanding, newest 4 stay in flight). Trailing lgkmcnt(0) at
// ph2/ph6 makes the cross-wave read-vs-restage WAR rigorous. Compiler's own
// fine-grained lgkmcnt covers read->MFMA deps (no manual per-phase waits).
// ---------------------------------------------------------------------------
#define BAR   asm volatile("s_barrier" ::: "memory")
#define LGKM0 do { asm volatile("s_waitcnt lgkmcnt(0)" ::: "memory");          \
                   __builtin_amdgcn_sched_barrier(0); } while (0)
#define VM4   do { asm volatile("s_waitcnt vmcnt(4)" ::: "memory");            \
                   __builtin_amdgcn_sched_barrier(0); } while (0)
#define VM0   do { asm volatile("s_waitcnt vmcnt(0)" ::: "memory");            \
                   __builtin_amdgcn_sched_barrier(0); } while (0)

__global__ __launch_bounds__(512, 2) void k_gemm(const u16* __restrict__ G,
                                                 const u16* __restrict__ C,
                                                 const float* __restrict__ bias,
                                                 float* __restrict__ y,
                                                 int n0) {
  __shared__ u16 lds[65536];   // 128 KB. Bytes: A(b)=b*32768, B(b)=65536+b*32768
  int t = threadIdx.x;
  int rb = blockIdx.x;
  int chunk = gridDim.x >> 3;
  int virt = (rb & 7) * chunk + (rb >> 3);
  int nn = n0 + (virt >> 7);
  int r7 = virt & 127;
  int o  = r7 >> 2;
  int vt = (r7 >> 1) & 1, lt = r7 & 1;
  int v0 = vt << 8, l0 = lt << 8;
  const u16* Cp = C + (size_t)((nn - n0) * 32 + o) * (512 * 2048);

  int lane = t & 63, wid = t >> 6;
  int l15 = lane & 15, g = lane >> 4;
  int wm = wid >> 2, wn = wid & 3;          // 2M x 4N wave grid

  // staging source (pre-swizzled slot), linear LDS dest
  int rr = t >> 3;                          // 0..63
  int sp = (t & 7) ^ (rr & 7);
  const u16* gA = G  + (size_t)(v0 + rr) * 2048 + sp * 8;
  const u16* gB = Cp + (size_t)(l0 + rr) * 2048 + sp * 8;
  char* ldsw = (char*)lds + (wid << 10);

#define STGA(b, T, h)                                                        \
  do {                                                                       \
    const u16* s_ = gA + (size_t)(h) * 262144 + (size_t)(T) * 64;            \
    gld16(s_,          ldsw + (b) * 32768 + (h) * 16384);                    \
    gld16(s_ + 131072, ldsw + (b) * 32768 + (h) * 16384 + 8192);             \
  } while (0)
#define STGB(b, T, h)                                                        \
  do {                                                                       \
    const u16* s_ = gB + (size_t)(h) * 262144 + (size_t)(T) * 64;            \
    gld16(s_,          ldsw + 65536 + (b) * 32768 + (h) * 16384);            \
    gld16(s_ + 131072, ldsw + 65536 + (b) * 32768 + (h) * 16384 + 8192);     \
  } while (0)

  // swizzled fragment read offsets
  int sx0 = (g ^ (l15 & 7)) << 4;
  int sx1 = ((4 | g) ^ (l15 & 7)) << 4;
  int aoff = (wm * 128 + l15) * 128;        // bytes
  int boff = (wn * 64 + l15) * 128;
  const char* ldsc = (const char*)lds;

  bf16x8 af[8][2], bf[4][2];
#define RDK0(b)                                                              \
  do {                                                                       \
    _Pragma("unroll") for (int m = 0; m < 8; ++m)                            \
      af[m][0] = *(const bf16x8*)(ldsc + (b) * 32768 + aoff + m * 2048 + sx0); \
    _Pragma("unroll") for (int n = 0; n < 4; ++n)                            \
      bf[n][0] = *(const bf16x8*)(ldsc + 65536 + (b) * 32768 + boff + n * 2048 + sx0); \
  } while (0)
#define RDK1(b)                                                              \
  do {                                                                       \
    _Pragma("unroll") for (int m = 0; m < 8; ++m)                            \
      af[m][1] = *(const bf16x8*)(ldsc + (b) * 32768 + aoff + m * 2048 + sx1); \
    _Pragma("unroll") for (int n = 0; n < 4; ++n)                            \
      bf[n][1] = *(const bf16x8*)(ldsc + 65536 + (b) * 32768 + boff + n * 2048 + sx1); \
  } while (0)

  f32x4 acc[8][4];
#pragma unroll
  for (int i = 0; i < 8; ++i)
#pragma unroll
    for (int j = 0; j < 4; ++j) {
      f32x4 z = {0.f, 0.f, 0.f, 0.f};
      acc[i][j] = z;
    }

#define CLUSTER(mh, ks)                                                      \
  do {                                                                       \
    __builtin_amdgcn_s_setprio(1);                                           \
    _Pragma("unroll") for (int m = 0; m < 4; ++m)                            \
    _Pragma("unroll") for (int n = 0; n < 4; ++n)                            \
      acc[(mh) * 4 + m][n] = __builtin_amdgcn_mfma_f32_16x16x32_bf16(        \
          af[(mh) * 4 + m][ks], bf[n][ks], acc[(mh) * 4 + m][n], 0, 0, 0);   \
    __builtin_amdgcn_s_setprio(0);                                           \
  } while (0)

  // prologue: tile0 (buf0) full + tile1 (buf1) Ah0,Ah1  (6 half-tiles)
  STGA(0, 0, 0); STGA(0, 0, 1); STGB(0, 0, 0); STGB(0, 0, 1);
  STGA(1, 1, 0); STGA(1, 1, 1);
  VM4;            // newest 4 = tile1's A halves -> tile0 fully landed
  BAR;

  for (int tt = 0; tt < 16; ++tt) {
    int t1 = 2 * tt + 1;
    int T2 = 2 * tt + 2;     // next buf0 tile
    int T3 = 2 * tt + 3;     // next buf1 tile
    bool more = (tt < 15);
    // ph1: reads k0(buf0); stage t1.Bh0
    RDK0(0);
    STGB(1, t1, 0);
    BAR; CLUSTER(0, 0); BAR;
    // ph2: reads k1(buf0); stage t1.Bh1; trailing LGKM0 (buf0 WAR-safe)
    RDK1(0);
    STGB(1, t1, 1);
    BAR; CLUSTER(1, 0); LGKM0; BAR;
    // ph3: stage T2.Ah0
    if (more) STGA(0, T2, 0);
    BAR; CLUSTER(0, 1); BAR;
    // ph4: stage T2.Ah1; VM4 -> t1 fully landed (12 outstanding, keep 4)
    if (more) {
      STGA(0, T2, 1);
      VM4;
    } else {
      VM0;                   // tail: drain t1's 8 before ph5 reads buf1
    }
    BAR; CLUSTER(1, 1); BAR;
    // ph5: reads k0(buf1); stage T2.Bh0
    RDK0(1);
    if (more) STGB(0, T2, 0);
    BAR; CLUSTER(0, 0); BAR;
    // ph6: reads k1(buf1); stage T2.Bh1; trailing LGKM0 (buf1 WAR-safe)
    RDK1(1);
    if (more) STGB(0, T2, 1);
    BAR; CLUSTER(1, 0); LGKM0; BAR;
    // ph7: stage T3.Ah0
    if (more) STGA(1, T3, 0);
    BAR; CLUSTER(0, 1); BAR;
    // ph8: stage T3.Ah1; VM4 -> T2 fully landed
    if (more) {
      STGA(1, T3, 1);
      VM4;
    }
    BAR; CLUSTER(1, 1); BAR;
  }
#undef STGA
#undef STGB
#undef RDK0
#undef RDK1
#undef CLUSTER

  float bo = bias[o];
#pragma unroll
  for (int mm = 0; mm < 8; ++mm)
#pragma unroll
    for (int n = 0; n < 4; ++n)
#pragma unroll
      for (int q = 0; q < 4; ++q) {
        int vv = v0 + wm * 128 + mm * 16 + g * 4 + q;
        int ll = l0 + wn * 64 + n * 16 + l15;
        size_t idx = (((size_t)(nn * 32 + o) * 512 + vv) << 9) + ll;
        y[idx] = acc[mm][n][q] + bo;
      }
}

// ---------------------------------------------------------------------------
extern "C" void kernel_launch(void* const* d_in, const int* in_sizes, int n_in,
                              void* d_out, int out_size, void* d_ws, size_t ws_size,
                              hipStream_t stream) {
  (void)in_sizes; (void)n_in; (void)out_size;
  const float* x    = (const float*)d_in[0];
  const float* adj  = (const float*)d_in[1];
  const float* W    = (const float*)d_in[2];
  const float* bias = (const float*)d_in[3];
  float* y = (float*)d_out;
  char* ws = (char*)d_ws;

  u16*   G  = (u16*)(ws);                  // 512*2048*2      = 2,097,152
  float* Af = (float*)(ws + 2097152);      // 512*512*4       = 1,048,576
  float* A2 = (float*)(ws + 3145728);      // 1,048,576
  float* A3 = (float*)(ws + 4194304);      // 1,048,576
  u16*   U  = (u16*)(ws + 5242880);        // 128*32*2        = 8,192
  u16*   C  = (u16*)(ws + 5251072);        // per-n: 32*512*2048*2 = 67,108,864
  const size_t fixed = 5251072;
  const size_t per_n = (size_t)32 * 512 * 2048 * 2;

  int grp = 0;
  const int cands[4] = {8, 4, 2, 1};
  for (int i = 0; i < 4; ++i)
    if (fixed + (size_t)cands[i] * per_n <= ws_size) { grp = cands[i]; break; }
  if (!grp) return;

  k_norm<<<dim3(512), dim3(256), 0, stream>>>(adj, Af);
  k_pow <<<dim3(128), dim3(256), 0, stream>>>(Af, Af, A2);
  k_pow <<<dim3(128), dim3(256), 0, stream>>>(A2, Af, A3);
  k_pack<<<dim3(512), dim3(256), 0, stream>>>(Af, A2, A3, G);
  k_u   <<<dim3(1),   dim3(128), 0, stream>>>(W, U);

  for (int n0 = 0; n0 < 8; n0 += grp) {
    k_mix <<<dim3(grp * 512), dim3(256), 0, stream>>>(x, U, C, n0);
    k_gemm<<<dim3(grp * 128), dim3(512), 0, stream>>>(G, C, bias, y, n0);
  }
}